// Round 8
// baseline (931.355 us; speedup 1.0000x reference)
//
#include <hip/hip_runtime.h>

#define BATCH 32
#define NMAT 1024
#define NBLK 1024            // 32 blocks per batch, 32 rows per block
#define SPB 32               // slabs per batch
#define N_ITERS 20
#define SHIFT 6.0f           // t' = exp(-10*D + 6) in [e^-4, e^6] — all normal e4m3
                             // (max 448). e^SHIFT cancels in t/S.

typedef float vf2 __attribute__((ext_vector_type(2)));

__device__ __forceinline__ float wave_allsum(float s) {
#pragma unroll
    for (int off = 1; off < 64; off <<= 1) s += __shfl_xor(s, off, 64);
    return s;
}

__device__ __forceinline__ float4 f4add(float4 a, float4 b) {
    return make_float4(a.x + b.x, a.y + b.y, a.z + b.z, a.w + b.w);
}

// Cross-wave combine of per-lane 16-col partials through LDS, then one
// coalesced float4 store into this block's private 4 KB slab. No atomics.
__device__ __forceinline__ void publish_slab(float4 (*pc)[256], const float* acc,
                                             int w, int L, float* dstSlab, int tid) {
    __syncthreads();
    pc[w][4 * L]     = make_float4(acc[0], acc[1], acc[2], acc[3]);
    pc[w][4 * L + 1] = make_float4(acc[4], acc[5], acc[6], acc[7]);
    pc[w][4 * L + 2] = make_float4(acc[8], acc[9], acc[10], acc[11]);
    pc[w][4 * L + 3] = make_float4(acc[12], acc[13], acc[14], acc[15]);
    __syncthreads();
    float4 o = f4add(f4add(pc[0][tid], pc[1][tid]), f4add(pc[2][tid], pc[3][tid]));
    ((float4*)dstSlab)[tid] = o;
}

// Iteration 0: read D (fp32, HBM), write E = fp8 e4m3 of exp(-10D+SHIFT),
// write first column partials (ev == 1) into slab j.
__global__ __launch_bounds__(256, 4) void pass1(const float* __restrict__ D,
                                                uint* __restrict__ E,
                                                float* __restrict__ P) {
    __shared__ float4 pc[4][256];
    const int j = blockIdx.x;
    const int w = threadIdx.x >> 6, L = threadIdx.x & 63;

    float acc[16];
#pragma unroll
    for (int q = 0; q < 16; ++q) acc[q] = 0.f;

#pragma unroll
    for (int i = 0; i < 8; ++i) {
        const int r = (j << 5) + w + (i << 2);
        const float4* Dr = (const float4*)(D + ((size_t)r << 10));
        float4 d0 = Dr[4 * L], d1 = Dr[4 * L + 1], d2 = Dr[4 * L + 2], d3 = Dr[4 * L + 3];
        float t[16];
        t[0]  = __expf(fmaf(d0.x, -10.f, SHIFT));
        t[1]  = __expf(fmaf(d0.y, -10.f, SHIFT));
        t[2]  = __expf(fmaf(d0.z, -10.f, SHIFT));
        t[3]  = __expf(fmaf(d0.w, -10.f, SHIFT));
        t[4]  = __expf(fmaf(d1.x, -10.f, SHIFT));
        t[5]  = __expf(fmaf(d1.y, -10.f, SHIFT));
        t[6]  = __expf(fmaf(d1.z, -10.f, SHIFT));
        t[7]  = __expf(fmaf(d1.w, -10.f, SHIFT));
        t[8]  = __expf(fmaf(d2.x, -10.f, SHIFT));
        t[9]  = __expf(fmaf(d2.y, -10.f, SHIFT));
        t[10] = __expf(fmaf(d2.z, -10.f, SHIFT));
        t[11] = __expf(fmaf(d2.w, -10.f, SHIFT));
        t[12] = __expf(fmaf(d3.x, -10.f, SHIFT));
        t[13] = __expf(fmaf(d3.y, -10.f, SHIFT));
        t[14] = __expf(fmaf(d3.z, -10.f, SHIFT));
        t[15] = __expf(fmaf(d3.w, -10.f, SHIFT));
        uint4 o;
        int wd = 0;
        wd = __builtin_amdgcn_cvt_pk_fp8_f32(t[0],  t[1],  wd, false);
        wd = __builtin_amdgcn_cvt_pk_fp8_f32(t[2],  t[3],  wd, true);  o.x = wd;
        wd = 0;
        wd = __builtin_amdgcn_cvt_pk_fp8_f32(t[4],  t[5],  wd, false);
        wd = __builtin_amdgcn_cvt_pk_fp8_f32(t[6],  t[7],  wd, true);  o.y = wd;
        wd = 0;
        wd = __builtin_amdgcn_cvt_pk_fp8_f32(t[8],  t[9],  wd, false);
        wd = __builtin_amdgcn_cvt_pk_fp8_f32(t[10], t[11], wd, true);  o.z = wd;
        wd = 0;
        wd = __builtin_amdgcn_cvt_pk_fp8_f32(t[12], t[13], wd, false);
        wd = __builtin_amdgcn_cvt_pk_fp8_f32(t[14], t[15], wd, true);  o.w = wd;
        ((uint4*)(E + ((size_t)r << 8)))[L] = o;

        float s0 = 0.f, s1 = 0.f, s2 = 0.f, s3 = 0.f;
#pragma unroll
        for (int q = 0; q < 4; ++q) {
            s0 += t[q]; s1 += t[4 + q]; s2 += t[8 + q]; s3 += t[12 + q];
        }
        const float s = wave_allsum((s0 + s1) + (s2 + s3));
        const float rs = __builtin_amdgcn_rcpf(s);
#pragma unroll
        for (int q = 0; q < 16; ++q) acc[q] = fmaf(t[q], rs, acc[q]);
    }
    publish_slab(pc, acc, w, L, P + ((size_t)j << 10), threadIdx.x);
}

// ev[b][m] = 1 / sum over the batch's 32 slabs.  256 blocks x 128 threads.
__global__ __launch_bounds__(128) void reduce_ev(const float* __restrict__ P,
                                                 float* __restrict__ ev) {
    const int g = blockIdx.x * 128 + threadIdx.x;   // 32768
    const int b = g >> 10, m = g & 1023;
    const float* Pb = P + (((size_t)b * SPB) << 10) + m;
    float s = 0.f;
#pragma unroll
    for (int k = 0; k < SPB; ++k) s += Pb[(size_t)k << 10];
    ev[g] = __builtin_amdgcn_rcpf(s);
}

// Iterations 1..19: read E (fp8) + ev, write new slab. LAST also writes loss
// slab Q (d reconstructed via log) and arms out[0].
template <bool LAST>
__global__ __launch_bounds__(256, 4) void pass_iter(const uint* __restrict__ E,
                                                    const float* __restrict__ ev_in,
                                                    float* __restrict__ P,
                                                    float* __restrict__ Qs,
                                                    float* __restrict__ out) {
    __shared__ float4 pc[4][256];
    const int j = blockIdx.x;
    const int b = j >> 5;
    const int w = threadIdx.x >> 6, L = threadIdx.x & 63;

    float ev[16];
    {
        const float4* Eb = (const float4*)(ev_in + (b << 10));
        float4 r0 = Eb[4 * L], r1 = Eb[4 * L + 1], r2 = Eb[4 * L + 2], r3 = Eb[4 * L + 3];
        ev[0] = r0.x;  ev[1] = r0.y;  ev[2] = r0.z;  ev[3] = r0.w;
        ev[4] = r1.x;  ev[5] = r1.y;  ev[6] = r1.z;  ev[7] = r1.w;
        ev[8] = r2.x;  ev[9] = r2.y;  ev[10] = r2.z; ev[11] = r2.w;
        ev[12] = r3.x; ev[13] = r3.y; ev[14] = r3.z; ev[15] = r3.w;
    }

    float acc[16], qacc[16];
#pragma unroll
    for (int q = 0; q < 16; ++q) { acc[q] = 0.f; qacc[q] = 0.f; }

#pragma unroll
    for (int i = 0; i < 8; ++i) {
        const int r = (j << 5) + w + (i << 2);
        const uint4 h = ((const uint4*)(E + ((size_t)r << 8)))[L];
        float t[16];
        {
            vf2 p;
            p = __builtin_amdgcn_cvt_pk_f32_fp8(h.x, false); t[0]  = p.x; t[1]  = p.y;
            p = __builtin_amdgcn_cvt_pk_f32_fp8(h.x, true);  t[2]  = p.x; t[3]  = p.y;
            p = __builtin_amdgcn_cvt_pk_f32_fp8(h.y, false); t[4]  = p.x; t[5]  = p.y;
            p = __builtin_amdgcn_cvt_pk_f32_fp8(h.y, true);  t[6]  = p.x; t[7]  = p.y;
            p = __builtin_amdgcn_cvt_pk_f32_fp8(h.z, false); t[8]  = p.x; t[9]  = p.y;
            p = __builtin_amdgcn_cvt_pk_f32_fp8(h.z, true);  t[10] = p.x; t[11] = p.y;
            p = __builtin_amdgcn_cvt_pk_f32_fp8(h.w, false); t[12] = p.x; t[13] = p.y;
            p = __builtin_amdgcn_cvt_pk_f32_fp8(h.w, true);  t[14] = p.x; t[15] = p.y;
        }
        float s0 = 0.f, s1 = 0.f, s2 = 0.f, s3 = 0.f;
#pragma unroll
        for (int q = 0; q < 4; ++q) {
            s0 = fmaf(t[q],      ev[q],      s0);
            s1 = fmaf(t[4 + q],  ev[4 + q],  s1);
            s2 = fmaf(t[8 + q],  ev[8 + q],  s2);
            s3 = fmaf(t[12 + q], ev[12 + q], s3);
        }
        const float s = wave_allsum((s0 + s1) + (s2 + s3));
        const float rs = __builtin_amdgcn_rcpf(s);
#pragma unroll
        for (int q = 0; q < 16; ++q) acc[q] = fmaf(t[q], rs, acc[q]);
        if (LAST) {
#pragma unroll
            for (int q = 0; q < 16; ++q) {
                const float d = (SHIFT - __logf(t[q])) * 0.1f;
                qacc[q] = fmaf(t[q] * d, rs, qacc[q]);
            }
        }
    }
    publish_slab(pc, acc, w, L, P + ((size_t)j << 10), threadIdx.x);
    if (LAST) {
        publish_slab(pc, qacc, w, L, Qs + ((size_t)j << 10), threadIdx.x);
        if (j == 0 && threadIdx.x == 0) out[0] = 0.f;   // arm loss atomics
    }
}

// loss = mean_b sum_m (ΣQ slabs)/(ΣP slabs).  128 blocks x 256 threads.
__global__ __launch_bounds__(256) void loss_final(const float* __restrict__ P,
                                                  const float* __restrict__ Qs,
                                                  float* __restrict__ out) {
    const int g = blockIdx.x * 256 + threadIdx.x;   // 32768
    const int b = g >> 10, m = g & 1023;
    const float* Pb = P + (((size_t)b * SPB) << 10) + m;
    const float* Qb = Qs + (((size_t)b * SPB) << 10) + m;
    float s = 0.f, q = 0.f;
#pragma unroll
    for (int k = 0; k < SPB; ++k) {
        s += Pb[(size_t)k << 10];
        q += Qb[(size_t)k << 10];
    }
    float c = q / s;
    c = wave_allsum(c);
    __shared__ float sm[4];
    const int w = threadIdx.x >> 6, L = threadIdx.x & 63;
    if (L == 0) sm[w] = c;
    __syncthreads();
    if (threadIdx.x == 0)
        atomicAdd(out, (sm[0] + sm[1] + sm[2] + sm[3]) * (1.0f / (float)BATCH));
}

extern "C" void kernel_launch(void* const* d_in, const int* in_sizes, int n_in,
                              void* d_out, int out_size, void* d_ws, size_t ws_size,
                              hipStream_t stream) {
    const float* D = (const float*)d_in[0];
    float* out = (float*)d_out;

    float* P  = (float*)d_ws;               // 1024 slabs x 4 KB = 4 MB
    float* Qs = P + (size_t)NBLK * NMAT;    // 4 MB
    float* ev = Qs + (size_t)NBLK * NMAT;   // 128 KB
    uint* E   = (uint*)(ev + BATCH * NMAT); // 32 MB fp8

    pass1<<<NBLK, 256, 0, stream>>>(D, E, P);
    for (int t = 1; t < N_ITERS - 1; ++t) {
        reduce_ev<<<256, 128, 0, stream>>>(P, ev);
        pass_iter<false><<<NBLK, 256, 0, stream>>>(E, ev, P, Qs, out);
    }
    reduce_ev<<<256, 128, 0, stream>>>(P, ev);
    pass_iter<true><<<NBLK, 256, 0, stream>>>(E, ev, P, Qs, out);
    loss_final<<<128, 256, 0, stream>>>(P, Qs, out);
}